// Round 1
// baseline (422.778 us; speedup 1.0000x reference)
//
#include <hip/hip_runtime.h>

// SpatialTransformer: B=16, H=W=256, C=64, OH=OW=256, fp32 in/out.
// One output pixel = 64 contiguous channels = 256 B.
// 16 threads/pixel, float4 per thread (16 B/lane coalescing sweet spot).
// 256-thread block = 16 consecutive pixels (uniform batch index -> scalar theta loads).

constexpr int B_  = 16;
constexpr int H_  = 256;
constexpr int W_  = 256;
constexpr int C_  = 64;
constexpr int OH_ = 256;
constexpr int OW_ = 256;

__global__ __launch_bounds__(256) void st_kernel(const float* __restrict__ image,
                                                 const float* __restrict__ theta,
                                                 float* __restrict__ out) {
    const int tid = blockIdx.x * 256 + threadIdx.x;
    const int p  = tid >> 4;   // output pixel index (b*OH*OW + oh*OW + ow)
    const int cg = tid & 15;   // channel group: 4 channels per thread

    const int ow = p & (OW_ - 1);
    const int oh = (p >> 8) & (OH_ - 1);
    const int b  = p >> 16;

    // theta[b] — b is uniform across the block, loads scalarize
    const float* t = theta + b * 6;
    const float t0 = t[0], t1 = t[1], t2 = t[2];
    const float t3 = t[3], t4 = t[4], t5 = t[5];

    // linspace(-1, 1, 256): step = 2/255
    const float xg = -1.0f + (2.0f / 255.0f) * (float)ow;
    const float yg = -1.0f + (2.0f / 255.0f) * (float)oh;

    const float x = 0.5f * (t0 * xg + t1 * yg + t2 + 1.0f) * (float)W_;
    const float y = 0.5f * (t3 * xg + t4 * yg + t5 + 1.0f) * (float)H_;

    const float fx = floorf(x);
    const float fy = floorf(y);
    const int ix = (int)fx;
    const int iy = (int)fy;
    const int x0 = min(max(ix, 0), W_ - 1);
    const int x1 = min(max(ix + 1, 0), W_ - 1);
    const int y0 = min(max(iy, 0), H_ - 1);
    const int y1 = min(max(iy + 1, 0), H_ - 1);

    // weights use the CLIPPED corner coords cast back to float (matches reference)
    const float x0f = (float)x0, x1f = (float)x1;
    const float y0f = (float)y0, y1f = (float)y1;
    const float wa = (x1f - x) * (y1f - y);
    const float wb = (x1f - x) * (y - y0f);
    const float wc = (x - x0f) * (y1f - y);
    const float wd = (x - x0f) * (y - y0f);

    const size_t ibase = (size_t)b * (H_ * W_ * C_);
    const float4* Pa = (const float4*)(image + ibase + ((size_t)(y0 * W_ + x0)) * C_) + cg;
    const float4* Pb = (const float4*)(image + ibase + ((size_t)(y1 * W_ + x0)) * C_) + cg;
    const float4* Pc = (const float4*)(image + ibase + ((size_t)(y0 * W_ + x1)) * C_) + cg;
    const float4* Pd = (const float4*)(image + ibase + ((size_t)(y1 * W_ + x1)) * C_) + cg;

    const float4 va = *Pa;
    const float4 vb = *Pb;
    const float4 vc = *Pc;
    const float4 vd = *Pd;

    float4 r;
    r.x = wa * va.x + wb * vb.x + wc * vc.x + wd * vd.x;
    r.y = wa * va.y + wb * vb.y + wc * vc.y + wd * vd.y;
    r.z = wa * va.z + wb * vb.z + wc * vc.z + wd * vd.z;
    r.w = wa * va.w + wb * vb.w + wc * vc.w + wd * vd.w;

    float4* po = (float4*)(out + (size_t)p * C_) + cg;
    *po = r;
}

extern "C" void kernel_launch(void* const* d_in, const int* in_sizes, int n_in,
                              void* d_out, int out_size, void* d_ws, size_t ws_size,
                              hipStream_t stream) {
    const float* image = (const float*)d_in[0];
    const float* theta = (const float*)d_in[1];
    float* out = (float*)d_out;

    // total threads = B*OH*OW*16 = 16,777,216 -> 65,536 blocks of 256
    const int total_pixels = B_ * OH_ * OW_;
    const int total_threads = total_pixels * 16;
    const int blocks = total_threads / 256;

    st_kernel<<<blocks, 256, 0, stream>>>(image, theta, out);
}